// Round 5
// baseline (435.590 us; speedup 1.0000x reference)
//
#include <hip/hip_runtime.h>

// PillarMaxPooling: Linear(10->64,nobias) -> BN1d(eval,eps=1e-3) -> ReLU ->
// segment_max -> clamp0.
//
// R1: 128M global atomicMax -> atomic-count bound (322 us).
// R2: per-point global scatter -> 4.4 GB cross-XCD RFO ping-pong.
// R3/R4: bucket sort + LDS-acc pool: pool VALU-bound (23 wave-inst/pt),
//        hist/split at 1 block/CU (12.5% occ) stuck at ~150 us combined.
// R5: deterministic counting sort (hist2D + column scans; NO global atomics),
//     split writes 20B fp16 payload records in sorted order; pool does
//     16 pts/group via mfma_f32_16x16x32_f16 (K-pad rows zeroed in B),
//     LDS atomicMax (stride-65 acc, trash row 128 absorbs pad slots).

#define C_IN   10
#define C_OUT  64
#define BSHIFT 7
#define BPILL  128
#define MAXNBP 2048              // supports M <= ~258k
#define SBLK   512
#define SCHUNK 4096
#define PPT    (SCHUNK / SBLK)   // 8 points per thread
#define REC    20                // payload record bytes: 10 x fp16

typedef _Float16 half8 __attribute__((ext_vector_type(8)));
typedef float    f32x4 __attribute__((ext_vector_type(4)));

// ---------- K1: per-chunk bucket histogram -> hist2d[chunk][bucket] ----------
__global__ __launch_bounds__(SBLK)
void k_hist(const int* __restrict__ idx, int* __restrict__ hist2d,
            int P, int NBpad) {
    __shared__ int lh[MAXNBP];
    const int t = threadIdx.x;
    for (int b = t; b < NBpad; b += SBLK) lh[b] = 0;
    __syncthreads();
    const int base = blockIdx.x * SCHUNK;
#pragma unroll
    for (int i = 0; i < PPT; ++i) {
        int p = base + i * SBLK + t;
        if (p < P) atomicAdd(&lh[idx[p] >> BSHIFT], 1);
    }
    __syncthreads();
    int* row = hist2d + (size_t)blockIdx.x * NBpad;
    for (int b = t; b < NBpad; b += SBLK) row[b] = lh[b];
}

// ---------- K2: column sums -> per-bucket totals ----------
__global__ __launch_bounds__(256)
void k_colsum(const int* __restrict__ hist2d, int* __restrict__ tots,
              int NSB, int NBpad) {
    int b = blockIdx.x * 256 + threadIdx.x;
    if (b >= NBpad) return;
    int tot = 0;
    for (int r = 0; r < NSB; ++r) tot += hist2d[(size_t)r * NBpad + b];
    tots[b] = tot;
}

// ---------- K3: aligned exclusive scan of totals -> starts[] ----------
__global__ __launch_bounds__(256)
void k_starts(const int* __restrict__ tots, int* __restrict__ starts, int NBpad) {
    __shared__ int tmp[256];
    const int t = threadIdx.x;
    int c[8]; int tot = 0;
#pragma unroll
    for (int j = 0; j < 8; ++j) {
        int e = t * 8 + j;
        c[j] = (e < NBpad) ? ((tots[e] + 15) & ~15) : 0;   // 16-align buckets
        tot += c[j];
    }
    tmp[t] = tot; __syncthreads();
#pragma unroll
    for (int off = 1; off < 256; off <<= 1) {
        int x = (t >= off) ? tmp[t - off] : 0;
        __syncthreads(); tmp[t] += x; __syncthreads();
    }
    int ex = tmp[t] - tot;
#pragma unroll
    for (int j = 0; j < 8; ++j) {
        int e = t * 8 + j;
        if (e < NBpad) starts[e] = ex;
        ex += c[j];
    }
    if (t == 255) starts[NBpad] = ex;
}

// ---------- K4: column exclusive scan: hist2d -> per-(chunk,bucket) bases ----
__global__ __launch_bounds__(256)
void k_colscan(int* __restrict__ hist2d, const int* __restrict__ starts,
               int NSB, int NBpad) {
    int b = blockIdx.x * 256 + threadIdx.x;
    if (b >= NBpad) return;
    int run = starts[b];
    for (int r = 0; r < NSB; ++r) {
        size_t o = (size_t)r * NBpad + b;
        int h = hist2d[o];
        hist2d[o] = run;
        run += h;
    }
}

// ---------- K5: split — rank via LDS only, write fp16 payload records -------
__global__ __launch_bounds__(SBLK)
void k_split(const int* __restrict__ idx, const float* __restrict__ gf,
             const int* __restrict__ bases2d, unsigned char* __restrict__ pay,
             unsigned char* __restrict__ mlarr, int P, int NBpad) {
    __shared__ int lh[MAXNBP];
    __shared__ int rbase[MAXNBP];
    const int t = threadIdx.x;
    for (int b = t; b < NBpad; b += SBLK) lh[b] = 0;
    __syncthreads();
    const int base = blockIdx.x * SCHUNK;
    int mm[PPT], rk[PPT];
#pragma unroll
    for (int i = 0; i < PPT; ++i) {
        int p = base + i * SBLK + t;
        mm[i] = -1;
        if (p < P) {
            int m = idx[p];
            mm[i] = m;
            rk[i] = atomicAdd(&lh[m >> BSHIFT], 1);
        }
    }
    __syncthreads();
    const int* brow = bases2d + (size_t)blockIdx.x * NBpad;
    for (int b = t; b < NBpad; b += SBLK) rbase[b] = brow[b];
    __syncthreads();
#pragma unroll
    for (int i = 0; i < PPT; ++i) {
        if (mm[i] >= 0) {
            int p = base + i * SBLK + t;
            int slot = rbase[mm[i] >> BSHIFT] + rk[i];
            const float* x = gf + (size_t)p * C_IN;
            unsigned short u[10];
#pragma unroll
            for (int k = 0; k < C_IN; ++k) {
                _Float16 hv = (_Float16)x[k];          // v_cvt_f16_f32 (RTNE)
                u[k] = __builtin_bit_cast(unsigned short, hv);
            }
            __builtin_memcpy(pay + (size_t)slot * REC, u, REC);
            mlarr[slot] = (unsigned char)(mm[i] & (BPILL - 1));
        }
    }
}

// ---------- K6: pool — MFMA over 16-point groups, LDS atomicMax --------------
__global__ __launch_bounds__(256)
void k_pool(const unsigned char* __restrict__ pay,
            const unsigned char* __restrict__ mlarr,
            const int* __restrict__ starts,
            const float* __restrict__ W,
            const float* __restrict__ gamma,
            const float* __restrict__ beta,
            const float* __restrict__ rmean,
            const float* __restrict__ rvar,
            float* __restrict__ out, int M) {
    __shared__ unsigned int acc[129 * 65];   // stride 65 spreads banks; row 128 = trash
    const int t = threadIdx.x;
    const int lane = t & 63;
    const int wv = t >> 6;
    const int n = lane & 15;                 // MFMA col (channel within tile)
    const int q = lane >> 4;                 // MFMA lane-quad

    for (int i = t; i < 129 * 65; i += 256) acc[i] = 0u;

    // B fragments (W rows k>=10 zeroed -> A K-pad garbage contributes x0)
    half8 bfrag[4];
    float inv[4], bia[4];
#pragma unroll
    for (int tt = 0; tt < 4; ++tt) {
        int c = tt * 16 + n;
#pragma unroll
        for (int j = 0; j < 8; ++j) {
            int k = q * 8 + j;
            bfrag[tt][j] = (k < C_IN) ? (_Float16)W[k * C_OUT + c] : (_Float16)0.f;
        }
        float is = gamma[c] * rsqrtf(rvar[c] + 1e-3f);
        inv[tt] = is;
        bia[tt] = fmaf(-rmean[c], is, beta[c]);
    }
    __syncthreads();

    const int s0 = starts[blockIdx.x], s1 = starts[blockIdx.x + 1];
    const unsigned int* ml4 = (const unsigned int*)mlarr;

    for (int rb = s0 + wv * 16; rb < s1; rb += 64) {
        // A fragment: lane holds 8 fp16 of point rb+n at k-octet (q&1).
        // Octets 2,3 duplicate 0,1 (k>=16 multiplied by zero B rows).
        half8 a;
        __builtin_memcpy(&a, pay + (size_t)(rb + n) * REC + (q & 1) * 16, 16);
        unsigned int mlp = ml4[(rb >> 2) + q];   // local pillar ids, rows 4q..4q+3
        f32x4 z = {0.f, 0.f, 0.f, 0.f};
        f32x4 d[4];
#pragma unroll
        for (int tt = 0; tt < 4; ++tt)
            d[tt] = __builtin_amdgcn_mfma_f32_16x16x32_f16(a, bfrag[tt], z, 0, 0, 0);
#pragma unroll
        for (int r = 0; r < 4; ++r) {            // C row = 4q + r = point
            unsigned int ml = (mlp >> (8 * r)) & 255u;
            ml = ml > 128u ? 128u : ml;          // pad slots (0xAA) -> trash row
            int abase = (int)ml * 65 + n;
#pragma unroll
            for (int tt = 0; tt < 4; ++tt) {
                float h = fmaxf(fmaf(d[tt][r], inv[tt], bia[tt]), 0.f);
                atomicMax(&acc[abase + tt * 16], __float_as_uint(h));
            }
        }
    }
    __syncthreads();

    // coalesced writeback of 128 pillars x 64 channels
    const int mbase = blockIdx.x * BPILL;
#pragma unroll
    for (int i = 0; i < (BPILL * C_OUT) / 256; ++i) {
        int w = i * 256 + t;
        int row = w >> 6, c = w & 63;
        int m = mbase + row;
        if (m < M) out[(size_t)m * C_OUT + c] = __uint_as_float(acc[row * 65 + c]);
    }
}

extern "C" void kernel_launch(void* const* d_in, const int* in_sizes, int n_in,
                              void* d_out, int out_size, void* d_ws, size_t ws_size,
                              hipStream_t stream) {
    const float* gf    = (const float*)d_in[0];
    const int*   idx   = (const int*)  d_in[1];
    const float* W     = (const float*)d_in[3];
    const float* gamma = (const float*)d_in[4];
    const float* beta  = (const float*)d_in[5];
    const float* rmean = (const float*)d_in[6];
    const float* rvar  = (const float*)d_in[7];
    float*       out   = (float*)d_out;

    const int P  = in_sizes[0] / C_IN;
    const int M  = out_size / C_OUT;
    const int NB    = (M + BPILL - 1) >> BSHIFT;    // 1563 for M=200k
    const int NBpad = (NB + 32) & ~31;              // 1568; > NB so starts[NB] valid
    const int NSB   = (P + SCHUNK - 1) / SCHUNK;    // 489

    char* ws = (char*)d_ws;
    auto align256 = [](size_t x) { return (x + 255) & ~(size_t)255; };
    int* hist2d = (int*)ws;  ws += align256((size_t)NSB * NBpad * 4);      // ~3.1 MB
    int* tots   = (int*)ws;  ws += align256((size_t)NBpad * 4);
    int* starts = (int*)ws;  ws += align256((size_t)(NBpad + 1) * 4);
    const size_t cap = (size_t)P + 16 * (size_t)NB;                        // incl. pads
    unsigned char* pay   = (unsigned char*)ws;  ws += align256(cap * REC + 64);  // ~40.5 MB
    unsigned char* mlarr = (unsigned char*)ws;                             // ~2 MB

    const int SCG = (NBpad + 255) / 256;

    k_hist   <<<NSB, SBLK, 0, stream>>>(idx, hist2d, P, NBpad);
    k_colsum <<<SCG, 256, 0, stream>>>(hist2d, tots, NSB, NBpad);
    k_starts <<<1,   256, 0, stream>>>(tots, starts, NBpad);
    k_colscan<<<SCG, 256, 0, stream>>>(hist2d, starts, NSB, NBpad);
    k_split  <<<NSB, SBLK, 0, stream>>>(idx, gf, hist2d, pay, mlarr, P, NBpad);
    k_pool   <<<NB,  256, 0, stream>>>(pay, mlarr, starts, W, gamma, beta,
                                       rmean, rvar, out, M);
}

// Round 6
// 279.418 us; speedup vs baseline: 1.5589x; 1.5589x over previous
//
#include <hip/hip_runtime.h>

// PillarMaxPooling: Linear(10->64,nobias) -> BN1d(eval,eps=1e-3) -> ReLU ->
// segment_max -> clamp0.
//
// R1: 128M global atomicMax -> atomic-count bound (322 us).
// R2: per-point global scatter -> 4.4 GB cross-XCD RFO ping-pong.
// R3/R4: bucket sort + LDS-acc pool: pool VALU-bound, sort latency-bound.
// R5: fp16 payload sort + MFMA pool works (absmax 0.031), but the two
//     column-scan kernels ran at 7 blocks(!) -> 117 us EACH at 0.3% occupancy.
// R6: single parallel column-scan (one block per bucket-column, LDS block
//     scan, ~6 blocks/CU); split adds starts[b] + column-local base.

#define C_IN   10
#define C_OUT  64
#define BSHIFT 7
#define BPILL  128
#define MAXNBP 2048              // supports M <= ~258k
#define SBLK   512
#define SCHUNK 4096
#define PPT    (SCHUNK / SBLK)   // 8 points per thread
#define REC    20                // payload record bytes: 10 x fp16

typedef _Float16 half8 __attribute__((ext_vector_type(8)));
typedef float    f32x4 __attribute__((ext_vector_type(4)));

// ---------- K1: per-chunk bucket histogram -> hist2d[chunk][bucket] ----------
__global__ __launch_bounds__(SBLK)
void k_hist(const int* __restrict__ idx, int* __restrict__ hist2d,
            int P, int NBpad) {
    __shared__ int lh[MAXNBP];
    const int t = threadIdx.x;
    for (int b = t; b < NBpad; b += SBLK) lh[b] = 0;
    __syncthreads();
    const int base = blockIdx.x * SCHUNK;
#pragma unroll
    for (int i = 0; i < PPT; ++i) {
        int p = base + i * SBLK + t;
        if (p < P) atomicAdd(&lh[idx[p] >> BSHIFT], 1);
    }
    __syncthreads();
    int* row = hist2d + (size_t)blockIdx.x * NBpad;
    for (int b = t; b < NBpad; b += SBLK) row[b] = lh[b];
}

// ---------- K2: parallel per-column exclusive scan (one block per column) ----
// hist2d[r][b] becomes the column-local exclusive prefix; tots[b] = column sum.
__global__ __launch_bounds__(256)
void k_colscan2(int* __restrict__ hist2d, int* __restrict__ tots,
                int NSB, int NBpad) {
    __shared__ int tmp[256];
    const int b = blockIdx.x;            // bucket column
    const int t = threadIdx.x;
    int v[4]; int tot = 0;               // rows 4t..4t+3 (NSB <= 1024)
#pragma unroll
    for (int j = 0; j < 4; ++j) {
        int r = t * 4 + j;
        v[j] = (r < NSB) ? hist2d[(size_t)r * NBpad + b] : 0;
        tot += v[j];
    }
    tmp[t] = tot; __syncthreads();
#pragma unroll
    for (int off = 1; off < 256; off <<= 1) {
        int x = (t >= off) ? tmp[t - off] : 0;
        __syncthreads(); tmp[t] += x; __syncthreads();
    }
    int ex = tmp[t] - tot;
#pragma unroll
    for (int j = 0; j < 4; ++j) {
        int r = t * 4 + j;
        if (r < NSB) hist2d[(size_t)r * NBpad + b] = ex;
        ex += v[j];
    }
    if (t == 255) tots[b] = ex;          // grand total of the column
}

// ---------- K3: aligned exclusive scan of totals -> starts[] ----------
__global__ __launch_bounds__(256)
void k_starts(const int* __restrict__ tots, int* __restrict__ starts, int NBpad) {
    __shared__ int tmp[256];
    const int t = threadIdx.x;
    int c[8]; int tot = 0;
#pragma unroll
    for (int j = 0; j < 8; ++j) {
        int e = t * 8 + j;
        c[j] = (e < NBpad) ? ((tots[e] + 15) & ~15) : 0;   // 16-align buckets
        tot += c[j];
    }
    tmp[t] = tot; __syncthreads();
#pragma unroll
    for (int off = 1; off < 256; off <<= 1) {
        int x = (t >= off) ? tmp[t - off] : 0;
        __syncthreads(); tmp[t] += x; __syncthreads();
    }
    int ex = tmp[t] - tot;
#pragma unroll
    for (int j = 0; j < 8; ++j) {
        int e = t * 8 + j;
        if (e < NBpad) starts[e] = ex;
        ex += c[j];
    }
    if (t == 255) starts[NBpad] = ex;
}

// ---------- K4: split — rank via LDS, write fp16 payload records -------------
__global__ __launch_bounds__(SBLK)
void k_split(const int* __restrict__ idx, const float* __restrict__ gf,
             const int* __restrict__ localbase2d, const int* __restrict__ starts,
             unsigned char* __restrict__ pay, unsigned char* __restrict__ mlarr,
             int P, int NBpad) {
    __shared__ int lh[MAXNBP];
    __shared__ int rbase[MAXNBP];
    const int t = threadIdx.x;
    for (int b = t; b < NBpad; b += SBLK) lh[b] = 0;
    __syncthreads();
    const int base = blockIdx.x * SCHUNK;
    int mm[PPT], rk[PPT];
#pragma unroll
    for (int i = 0; i < PPT; ++i) {
        int p = base + i * SBLK + t;
        mm[i] = -1;
        if (p < P) {
            int m = idx[p];
            mm[i] = m;
            rk[i] = atomicAdd(&lh[m >> BSHIFT], 1);
        }
    }
    __syncthreads();
    const int* brow = localbase2d + (size_t)blockIdx.x * NBpad;
    for (int b = t; b < NBpad; b += SBLK) rbase[b] = brow[b] + starts[b];
    __syncthreads();
#pragma unroll
    for (int i = 0; i < PPT; ++i) {
        if (mm[i] >= 0) {
            int p = base + i * SBLK + t;
            int slot = rbase[mm[i] >> BSHIFT] + rk[i];
            const float* x = gf + (size_t)p * C_IN;
            unsigned short u[10];
#pragma unroll
            for (int k = 0; k < C_IN; ++k) {
                _Float16 hv = (_Float16)x[k];          // v_cvt_f16_f32 (RTNE)
                u[k] = __builtin_bit_cast(unsigned short, hv);
            }
            __builtin_memcpy(pay + (size_t)slot * REC, u, REC);
            mlarr[slot] = (unsigned char)(mm[i] & (BPILL - 1));
        }
    }
}

// ---------- K5: pool — MFMA over 16-point groups, LDS atomicMax --------------
__global__ __launch_bounds__(256)
void k_pool(const unsigned char* __restrict__ pay,
            const unsigned char* __restrict__ mlarr,
            const int* __restrict__ starts,
            const float* __restrict__ W,
            const float* __restrict__ gamma,
            const float* __restrict__ beta,
            const float* __restrict__ rmean,
            const float* __restrict__ rvar,
            float* __restrict__ out, int M) {
    __shared__ unsigned int acc[129 * 65];   // stride 65 spreads banks; row 128 = trash
    const int t = threadIdx.x;
    const int lane = t & 63;
    const int wv = t >> 6;
    const int n = lane & 15;                 // MFMA col (channel within tile)
    const int q = lane >> 4;                 // MFMA lane-quad

    for (int i = t; i < 129 * 65; i += 256) acc[i] = 0u;

    // B fragments (W rows k>=10 zeroed -> A K-pad garbage contributes x0)
    half8 bfrag[4];
    float inv[4], bia[4];
#pragma unroll
    for (int tt = 0; tt < 4; ++tt) {
        int c = tt * 16 + n;
#pragma unroll
        for (int j = 0; j < 8; ++j) {
            int k = q * 8 + j;
            bfrag[tt][j] = (k < C_IN) ? (_Float16)W[k * C_OUT + c] : (_Float16)0.f;
        }
        float is = gamma[c] * rsqrtf(rvar[c] + 1e-3f);
        inv[tt] = is;
        bia[tt] = fmaf(-rmean[c], is, beta[c]);
    }
    __syncthreads();

    const int s0 = starts[blockIdx.x], s1 = starts[blockIdx.x + 1];
    const unsigned int* ml4 = (const unsigned int*)mlarr;

    for (int rb = s0 + wv * 16; rb < s1; rb += 64) {
        // A fragment: lane holds 8 fp16 of point rb+n at k-octet (q&1).
        // Octets 2,3 duplicate 0,1 (k>=16 multiplied by zero B rows).
        half8 a;
        __builtin_memcpy(&a, pay + (size_t)(rb + n) * REC + (q & 1) * 16, 16);
        unsigned int mlp = ml4[(rb >> 2) + q];   // local pillar ids, rows 4q..4q+3
        f32x4 z = {0.f, 0.f, 0.f, 0.f};
        f32x4 d[4];
#pragma unroll
        for (int tt = 0; tt < 4; ++tt)
            d[tt] = __builtin_amdgcn_mfma_f32_16x16x32_f16(a, bfrag[tt], z, 0, 0, 0);
#pragma unroll
        for (int r = 0; r < 4; ++r) {            // C row = 4q + r = point
            unsigned int ml = (mlp >> (8 * r)) & 255u;
            ml = ml > 128u ? 128u : ml;          // pad slots (0xAA) -> trash row
            int abase = (int)ml * 65 + n;
#pragma unroll
            for (int tt = 0; tt < 4; ++tt) {
                float h = fmaxf(fmaf(d[tt][r], inv[tt], bia[tt]), 0.f);
                atomicMax(&acc[abase + tt * 16], __float_as_uint(h));
            }
        }
    }
    __syncthreads();

    // coalesced writeback of 128 pillars x 64 channels
    const int mbase = blockIdx.x * BPILL;
#pragma unroll
    for (int i = 0; i < (BPILL * C_OUT) / 256; ++i) {
        int w = i * 256 + t;
        int row = w >> 6, c = w & 63;
        int m = mbase + row;
        if (m < M) out[(size_t)m * C_OUT + c] = __uint_as_float(acc[row * 65 + c]);
    }
}

extern "C" void kernel_launch(void* const* d_in, const int* in_sizes, int n_in,
                              void* d_out, int out_size, void* d_ws, size_t ws_size,
                              hipStream_t stream) {
    const float* gf    = (const float*)d_in[0];
    const int*   idx   = (const int*)  d_in[1];
    const float* W     = (const float*)d_in[3];
    const float* gamma = (const float*)d_in[4];
    const float* beta  = (const float*)d_in[5];
    const float* rmean = (const float*)d_in[6];
    const float* rvar  = (const float*)d_in[7];
    float*       out   = (float*)d_out;

    const int P  = in_sizes[0] / C_IN;
    const int M  = out_size / C_OUT;
    const int NB    = (M + BPILL - 1) >> BSHIFT;    // 1563 for M=200k
    const int NBpad = (NB + 32) & ~31;              // 1568; > NB so starts[NB] valid
    const int NSB   = (P + SCHUNK - 1) / SCHUNK;    // 489 (must be <= 1024)

    char* ws = (char*)d_ws;
    auto align256 = [](size_t x) { return (x + 255) & ~(size_t)255; };
    int* hist2d = (int*)ws;  ws += align256((size_t)NSB * NBpad * 4);      // ~3.1 MB
    int* tots   = (int*)ws;  ws += align256((size_t)NBpad * 4);
    int* starts = (int*)ws;  ws += align256((size_t)(NBpad + 1) * 4);
    const size_t cap = (size_t)P + 16 * (size_t)NB;                        // incl. pads
    unsigned char* pay   = (unsigned char*)ws;  ws += align256(cap * REC + 64);  // ~40.5 MB
    unsigned char* mlarr = (unsigned char*)ws;                             // ~2 MB

    k_hist    <<<NSB,   SBLK, 0, stream>>>(idx, hist2d, P, NBpad);
    k_colscan2<<<NBpad, 256, 0, stream>>>(hist2d, tots, NSB, NBpad);
    k_starts  <<<1,     256, 0, stream>>>(tots, starts, NBpad);
    k_split   <<<NSB,   SBLK, 0, stream>>>(idx, gf, hist2d, starts, pay, mlarr, P, NBpad);
    k_pool    <<<NB,    256, 0, stream>>>(pay, mlarr, starts, W, gamma, beta,
                                          rmean, rvar, out, M);
}

// Round 7
// 264.602 us; speedup vs baseline: 1.6462x; 1.0560x over previous
//
#include <hip/hip_runtime.h>

// PillarMaxPooling: Linear(10->64,nobias) -> BN1d(eval,eps=1e-3) -> ReLU ->
// segment_max -> clamp0.
//
// R1: 128M global atomicMax -> atomic-count bound (322 us).
// R2: per-point global scatter -> 4.4 GB cross-XCD RFO ping-pong.
// R3/R4: bucket sort + LDS-acc pool: pool VALU-bound, sort latency-bound.
// R5: fp16 payload sort + MFMA pool (absmax 0.031); scans at 0.3% occ.
// R6: parallel column scan; split now top: 100 us, WRITE 162 MB (3.4x amp —
//     20B records evict whole lines; adjacent runs on different XCDs).
// R7: max is order-invariant -> drop deterministic hist2d machinery AND the
//     40MB payload round-trip. Split scatters 4B tokens (pid|ml<<24) after a
//     per-(block,bucket) global reservation; pool gathers A-fragments
//     directly from gf (L3-resident) into the proven MFMA structure. Pad
//     slots get sentinel ml=128 -> trash accumulator row.

#define C_IN   10
#define C_OUT  64
#define BSHIFT 7
#define BPILL  128
#define MAXNBP 2048              // supports M <= ~258k
#define SBLK   512
#define SCHUNK 4096
#define PPT    (SCHUNK / SBLK)   // 8 points per thread

typedef _Float16 half8 __attribute__((ext_vector_type(8)));
typedef float    f32x4 __attribute__((ext_vector_type(4)));

// ---------- K1: bucket histogram -> global tots (LDS-privatized) ----------
__global__ __launch_bounds__(SBLK)
void k_hist(const int* __restrict__ idx, int* __restrict__ tots,
            int P, int NBpad) {
    __shared__ int lh[MAXNBP];
    const int t = threadIdx.x;
    for (int b = t; b < NBpad; b += SBLK) lh[b] = 0;
    __syncthreads();
    const int base = blockIdx.x * SCHUNK;
#pragma unroll
    for (int i = 0; i < PPT; ++i) {
        int p = base + i * SBLK + t;
        if (p < P) atomicAdd(&lh[idx[p] >> BSHIFT], 1);
    }
    __syncthreads();
    for (int b = t; b < NBpad; b += SBLK) {
        int h = lh[b];
        if (h) atomicAdd(&tots[b], h);
    }
}

// ---------- K2: aligned exclusive scan of tots -> starts[] + cursor[] -------
__global__ __launch_bounds__(256)
void k_starts(const int* __restrict__ tots, int* __restrict__ starts,
              int* __restrict__ cursor, int NBpad) {
    __shared__ int tmp[256];
    const int t = threadIdx.x;
    int c[8]; int tot = 0;
#pragma unroll
    for (int j = 0; j < 8; ++j) {
        int e = t * 8 + j;
        c[j] = (e < NBpad) ? ((tots[e] + 15) & ~15) : 0;   // 16-align buckets
        tot += c[j];
    }
    tmp[t] = tot; __syncthreads();
#pragma unroll
    for (int off = 1; off < 256; off <<= 1) {
        int x = (t >= off) ? tmp[t - off] : 0;
        __syncthreads(); tmp[t] += x; __syncthreads();
    }
    int ex = tmp[t] - tot;
#pragma unroll
    for (int j = 0; j < 8; ++j) {
        int e = t * 8 + j;
        if (e < NBpad) { starts[e] = ex; cursor[e] = ex; }
        ex += c[j];
    }
    if (t == 255) starts[NBpad] = ex;
}

// ---------- K3: fill pad slots with sentinel (ml=128 -> trash row) ----------
__global__ __launch_bounds__(256)
void k_padfill(const int* __restrict__ tots, const int* __restrict__ starts,
               unsigned int* __restrict__ sorted, int NBpad) {
    int b = blockIdx.x * 256 + threadIdx.x;
    if (b >= NBpad) return;
    int s = starts[b] + tots[b];
    int e = starts[b + 1];
    for (int i = s; i < e; ++i) sorted[i] = 128u << 24;   // pid=0, ml=128
}

// ---------- K4: split — LDS hist, one global reservation per (block,bucket),
// ----------      scatter 4B tokens pid | ml<<24 --------------------------
__global__ __launch_bounds__(SBLK)
void k_split(const int* __restrict__ idx, int* __restrict__ cursor,
             unsigned int* __restrict__ sorted, int P, int NBpad) {
    __shared__ int lh[MAXNBP];
    __shared__ int rbase[MAXNBP];
    const int t = threadIdx.x;
    for (int b = t; b < NBpad; b += SBLK) lh[b] = 0;
    __syncthreads();
    const int base = blockIdx.x * SCHUNK;
    int mm[PPT];
#pragma unroll
    for (int i = 0; i < PPT; ++i) {
        int p = base + i * SBLK + t;
        mm[i] = (p < P) ? idx[p] : -1;
        if (mm[i] >= 0) atomicAdd(&lh[mm[i] >> BSHIFT], 1);
    }
    __syncthreads();
    for (int b = t; b < NBpad; b += SBLK) {
        int h = lh[b];
        rbase[b] = h ? atomicAdd(&cursor[b], h) : 0;
        lh[b] = 0;
    }
    __syncthreads();
#pragma unroll
    for (int i = 0; i < PPT; ++i) {
        if (mm[i] >= 0) {
            int p = base + i * SBLK + t;
            int b = mm[i] >> BSHIFT;
            int slot = rbase[b] + atomicAdd(&lh[b], 1);
            sorted[slot] = (unsigned)p | ((unsigned)(mm[i] & (BPILL - 1)) << 24);
        }
    }
}

// ---------- K5: pool — gather gf directly, MFMA, LDS atomicMax --------------
__global__ __launch_bounds__(256)
void k_pool(const float* __restrict__ gf,
            const unsigned int* __restrict__ sorted,
            const int* __restrict__ starts,
            const float* __restrict__ W,
            const float* __restrict__ gamma,
            const float* __restrict__ beta,
            const float* __restrict__ rmean,
            const float* __restrict__ rvar,
            float* __restrict__ out, int M) {
    __shared__ unsigned int acc[129 * 65];   // stride 65; row 128 = trash (pads)
    const int t = threadIdx.x;
    const int lane = t & 63;
    const int wv = t >> 6;
    const int n = lane & 15;                 // MFMA row (point within 16-group)
    const int q = lane >> 4;                 // lane-quad -> k-octet

    for (int i = t; i < 129 * 65; i += 256) acc[i] = 0u;

    // B fragments: W rows k>=10 zeroed -> A K-padding is free
    half8 bfrag[4];
    float inv[4], bia[4];
#pragma unroll
    for (int tt = 0; tt < 4; ++tt) {
        int c = tt * 16 + n;
#pragma unroll
        for (int j = 0; j < 8; ++j) {
            int k = q * 8 + j;
            bfrag[tt][j] = (k < C_IN) ? (_Float16)W[k * C_OUT + c] : (_Float16)0.f;
        }
        float is = gamma[c] * rsqrtf(rvar[c] + 1e-3f);
        inv[tt] = is;
        bia[tt] = fmaf(-rmean[c], is, beta[c]);
    }
    __syncthreads();

    const int s0 = starts[blockIdx.x], s1 = starts[blockIdx.x + 1];
    const float2* gf2 = (const float2*)gf;

    for (int rb = s0 + wv * 16; rb < s1; rb += 64) {
        // token of this lane's point (row n); q-groups read duplicate words
        const unsigned v = sorted[rb + n];
        const int pid5 = (int)(v & 0xFFFFFFu) * 5;   // float2-unit base

        // A fragment: lane supplies k-octet q of point n. k>=10 -> zero.
        half8 a = (half8)(_Float16)0.f;
        if (q == 0) {
            float2 x0 = gf2[pid5 + 0], x1 = gf2[pid5 + 1];
            float2 x2 = gf2[pid5 + 2], x3 = gf2[pid5 + 3];
            a[0] = (_Float16)x0.x; a[1] = (_Float16)x0.y;
            a[2] = (_Float16)x1.x; a[3] = (_Float16)x1.y;
            a[4] = (_Float16)x2.x; a[5] = (_Float16)x2.y;
            a[6] = (_Float16)x3.x; a[7] = (_Float16)x3.y;
        } else if (q == 1) {
            float2 x4 = gf2[pid5 + 4];
            a[0] = (_Float16)x4.x; a[1] = (_Float16)x4.y;   // k=8,9
        }
        f32x4 z = {0.f, 0.f, 0.f, 0.f};
        f32x4 d[4];
#pragma unroll
        for (int tt = 0; tt < 4; ++tt)
            d[tt] = __builtin_amdgcn_mfma_f32_16x16x32_f16(a, bfrag[tt], z, 0, 0, 0);
#pragma unroll
        for (int r = 0; r < 4; ++r) {            // C row = 4q + r = point
            unsigned vr = __shfl(v, (q << 2) + r);   // that point's token
            int abase = (int)(vr >> 24) * 65 + n;    // ml (128 => trash row)
#pragma unroll
            for (int tt = 0; tt < 4; ++tt) {
                float h = fmaxf(fmaf(d[tt][r], inv[tt], bia[tt]), 0.f);
                atomicMax(&acc[abase + tt * 16], __float_as_uint(h));
            }
        }
    }
    __syncthreads();

    // coalesced writeback of 128 pillars x 64 channels
    const int mbase = blockIdx.x * BPILL;
#pragma unroll
    for (int i = 0; i < (BPILL * C_OUT) / 256; ++i) {
        int w = i * 256 + t;
        int row = w >> 6, c = w & 63;
        int m = mbase + row;
        if (m < M) out[(size_t)m * C_OUT + c] = __uint_as_float(acc[row * 65 + c]);
    }
}

extern "C" void kernel_launch(void* const* d_in, const int* in_sizes, int n_in,
                              void* d_out, int out_size, void* d_ws, size_t ws_size,
                              hipStream_t stream) {
    const float* gf    = (const float*)d_in[0];
    const int*   idx   = (const int*)  d_in[1];
    const float* W     = (const float*)d_in[3];
    const float* gamma = (const float*)d_in[4];
    const float* beta  = (const float*)d_in[5];
    const float* rmean = (const float*)d_in[6];
    const float* rvar  = (const float*)d_in[7];
    float*       out   = (float*)d_out;

    const int P  = in_sizes[0] / C_IN;
    const int M  = out_size / C_OUT;
    const int NB    = (M + BPILL - 1) >> BSHIFT;    // 1563 for M=200k
    const int NBpad = (NB + 32) & ~31;              // 1568 (> NB, starts[NB] valid)
    const int NSB   = (P + SCHUNK - 1) / SCHUNK;    // 489

    char* ws = (char*)d_ws;
    auto align256 = [](size_t x) { return (x + 255) & ~(size_t)255; };
    int* tots   = (int*)ws;  ws += align256((size_t)NBpad * 4);
    int* starts = (int*)ws;  ws += align256((size_t)(NBpad + 1) * 4);
    int* cursor = (int*)ws;  ws += align256((size_t)NBpad * 4);
    unsigned int* sorted = (unsigned int*)ws;       // P + 16*NB u32 (~8.2 MB)

    hipMemsetAsync(tots, 0, (size_t)NBpad * 4, stream);
    k_hist   <<<NSB, SBLK, 0, stream>>>(idx, tots, P, NBpad);
    k_starts <<<1,   256, 0, stream>>>(tots, starts, cursor, NBpad);
    k_padfill<<<(NBpad + 255) / 256, 256, 0, stream>>>(tots, starts, sorted, NBpad);
    k_split  <<<NSB, SBLK, 0, stream>>>(idx, cursor, sorted, P, NBpad);
    k_pool   <<<NB,  256, 0, stream>>>(gf, sorted, starts, W, gamma, beta,
                                       rmean, rvar, out, M);
}

// Round 8
// 262.514 us; speedup vs baseline: 1.6593x; 1.0080x over previous
//
#include <hip/hip_runtime.h>

// PillarMaxPooling: Linear(10->64,nobias) -> BN1d(eval,eps=1e-3) -> ReLU ->
// segment_max -> clamp0.
//
// R1: 128M global atomicMax -> atomic-count bound (322 us).
// R2: per-point global scatter -> 4.4 GB cross-XCD RFO ping-pong.
// R5: fp16 payload sort + MFMA pool; R6: parallel scans; R7: 4B tokens +
//     direct gf gather. Pool 104 us: 50%-capped occupancy (256thr x 33.5KB),
//     quarter-wave gather, 3.9M LDS conflicts; split lines ping-pong XCDs.
// R8: pool = 512 thr (8 waves share acc -> 100% occ cap) + lane-per-point
//     gather (full-wave loads, pkrtz, 5 shfls/group to MFMA A-layout);
//     sort = 8 block-keyed regions (blockIdx&7 ~ XCD) so token lines are
//     written by one region only; 2048-pt chunks -> 8 blocks/CU.
//     Pool wave w consumes region w's sub-range of its bucket.

#define C_IN   10
#define C_OUT  64
#define BSHIFT 7
#define BPILL  128
#define MAXNBP 2048              // supports M <= ~258k
#define NREG   8
#define SBLK   256
#define SCHUNK 2048
#define PPT    (SCHUNK / SBLK)   // 8 points per thread
#define PBLK   512
#define SENT   (128u << 24)

typedef _Float16 half8 __attribute__((ext_vector_type(8)));
typedef float    f32x4 __attribute__((ext_vector_type(4)));

// ---------- K1: bucket histogram -> tots[region][bucket] ----------
__global__ __launch_bounds__(SBLK)
void k_hist(const int* __restrict__ idx, int* __restrict__ tots,
            int P, int NBpad) {
    __shared__ int lh[MAXNBP];
    const int t = threadIdx.x;
    for (int b = t; b < NBpad; b += SBLK) lh[b] = 0;
    __syncthreads();
    const int base = blockIdx.x * SCHUNK;
#pragma unroll
    for (int i = 0; i < PPT; ++i) {
        int p = base + i * SBLK + t;
        if (p < P) atomicAdd(&lh[idx[p] >> BSHIFT], 1);
    }
    __syncthreads();
    int* row = tots + (size_t)(blockIdx.x & (NREG - 1)) * NBpad;
    for (int b = t; b < NBpad; b += SBLK) {
        int h = lh[b];
        if (h) atomicAdd(&row[b], h);
    }
}

// ---------- K2: exclusive scan over E=NREG*NBpad entries (16-aligned) -------
__global__ __launch_bounds__(256)
void k_scan(const int* __restrict__ tots, int* __restrict__ starts,
            int* __restrict__ cursor, int E) {
    __shared__ int tmp[256];
    const int t = threadIdx.x;
    const int C = (E + 255) / 256;
    int my = 0;
    for (int j = 0; j < C; ++j) {
        int e = t * C + j;
        if (e < E) my += (tots[e] + 15) & ~15;
    }
    tmp[t] = my; __syncthreads();
#pragma unroll
    for (int off = 1; off < 256; off <<= 1) {
        int x = (t >= off) ? tmp[t - off] : 0;
        __syncthreads(); tmp[t] += x; __syncthreads();
    }
    int ex = tmp[t] - my;
    for (int j = 0; j < C; ++j) {
        int e = t * C + j;
        if (e < E) {
            starts[e] = ex; cursor[e] = ex;
            ex += (tots[e] + 15) & ~15;
        }
    }
    if (t == 255) starts[E] = ex;
}

// ---------- K3: sentinel-fill pad slots (ml=128 -> trash row) ----------
__global__ __launch_bounds__(256)
void k_padfill(const int* __restrict__ tots, const int* __restrict__ starts,
               unsigned int* __restrict__ sorted, int E) {
    int e = blockIdx.x * 256 + threadIdx.x;
    if (e >= E) return;
    int s = starts[e] + tots[e];
    int e1 = starts[e + 1];
    for (int i = s; i < e1; ++i) sorted[i] = SENT;
}

// ---------- K4: split — region-keyed reservation, scatter 4B tokens ---------
__global__ __launch_bounds__(SBLK)
void k_split(const int* __restrict__ idx, int* __restrict__ cursor,
             unsigned int* __restrict__ sorted, int P, int NBpad) {
    __shared__ int lh[MAXNBP];
    __shared__ int rbase[MAXNBP];
    const int t = threadIdx.x;
    for (int b = t; b < NBpad; b += SBLK) lh[b] = 0;
    __syncthreads();
    const int base = blockIdx.x * SCHUNK;
    int mm[PPT];
#pragma unroll
    for (int i = 0; i < PPT; ++i) {
        int p = base + i * SBLK + t;
        mm[i] = (p < P) ? idx[p] : -1;
        if (mm[i] >= 0) atomicAdd(&lh[mm[i] >> BSHIFT], 1);
    }
    __syncthreads();
    int* crow = cursor + (size_t)(blockIdx.x & (NREG - 1)) * NBpad;
    for (int b = t; b < NBpad; b += SBLK) {
        int h = lh[b];
        rbase[b] = h ? atomicAdd(&crow[b], h) : 0;
        lh[b] = 0;
    }
    __syncthreads();
#pragma unroll
    for (int i = 0; i < PPT; ++i) {
        if (mm[i] >= 0) {
            int p = base + i * SBLK + t;
            int b = mm[i] >> BSHIFT;
            int slot = rbase[b] + atomicAdd(&lh[b], 1);
            sorted[slot] = (unsigned)p | ((unsigned)(mm[i] & (BPILL - 1)) << 24);
        }
    }
}

// ---------- K5: pool — lane-per-point gather, MFMA, LDS atomicMax -----------
__global__ __launch_bounds__(PBLK, 8)
void k_pool(const float* __restrict__ gf,
            const unsigned int* __restrict__ sorted,
            const int* __restrict__ starts,
            const float* __restrict__ W,
            const float* __restrict__ gamma,
            const float* __restrict__ beta,
            const float* __restrict__ rmean,
            const float* __restrict__ rvar,
            float* __restrict__ out, int M, int NBpad) {
    __shared__ unsigned int acc[129 * 65];   // stride 65; row 128 = trash (pads)
    const int t = threadIdx.x;
    const int lane = t & 63;
    const int wv = t >> 6;                   // wave == region 0..7
    const int n = lane & 15;
    const int q = lane >> 4;

    for (int i = t; i < 129 * 65; i += PBLK) acc[i] = 0u;

    // B fragments: W rows k>=10 zeroed -> A K-padding free
    half8 bfrag[4];
    float inv[4], bia[4];
#pragma unroll
    for (int tt = 0; tt < 4; ++tt) {
        int c = tt * 16 + n;
#pragma unroll
        for (int j = 0; j < 8; ++j) {
            int k = q * 8 + j;
            bfrag[tt][j] = (k < C_IN) ? (_Float16)W[k * C_OUT + c] : (_Float16)0.f;
        }
        float is = gamma[c] * rsqrtf(rvar[c] + 1e-3f);
        inv[tt] = is;
        bia[tt] = fmaf(-rmean[c], is, beta[c]);
    }
    __syncthreads();

    const int e  = wv * NBpad + blockIdx.x;  // this wave's (region,bucket) entry
    const int s0 = starts[e];
    const int s1 = starts[e + 1];            // padded end (contiguous scan)
    const float2* gf2 = (const float2*)gf;

    for (int rb = s0; rb < s1; rb += 64) {
        // lane-per-point: full-wave 40B contiguous gather + packed cvt
        unsigned v = (rb + lane < s1) ? sorted[rb + lane] : SENT;
        const float2* src = gf2 + (size_t)(v & 0xFFFFFFu) * 5;
        float2 x0 = src[0], x1 = src[1], x2 = src[2], x3 = src[3], x4 = src[4];
        int u0 = __builtin_bit_cast(int, __builtin_amdgcn_cvt_pkrtz(x0.x, x0.y));
        int u1 = __builtin_bit_cast(int, __builtin_amdgcn_cvt_pkrtz(x1.x, x1.y));
        int u2 = __builtin_bit_cast(int, __builtin_amdgcn_cvt_pkrtz(x2.x, x2.y));
        int u3 = __builtin_bit_cast(int, __builtin_amdgcn_cvt_pkrtz(x3.x, x3.y));
        int u4 = __builtin_bit_cast(int, __builtin_amdgcn_cvt_pkrtz(x4.x, x4.y));

        const int ng = min(4, (s1 - rb) >> 4);   // groups of 16 (range 16-aligned)
#pragma unroll
        for (int g = 0; g < 4; ++g) {
            if (g >= ng) break;                  // wave-uniform
            const int sl = (g << 4) + n;         // source lane: point g*16+n
            int b0 = __shfl(u0, sl, 64);
            int b1 = __shfl(u1, sl, 64);
            int b2 = __shfl(u2, sl, 64);
            int b3 = __shfl(u3, sl, 64);
            int b4 = __shfl(u4, sl, 64);
            int4 a32;
            a32.x = (q == 0) ? b0 : ((q == 1) ? b4 : 0);
            a32.y = (q == 0) ? b1 : 0;
            a32.z = (q == 0) ? b2 : 0;
            a32.w = (q == 0) ? b3 : 0;
            half8 a = __builtin_bit_cast(half8, a32);
            f32x4 z = {0.f, 0.f, 0.f, 0.f};
            f32x4 d0 = __builtin_amdgcn_mfma_f32_16x16x32_f16(a, bfrag[0], z, 0, 0, 0);
            f32x4 d1 = __builtin_amdgcn_mfma_f32_16x16x32_f16(a, bfrag[1], z, 0, 0, 0);
            f32x4 d2 = __builtin_amdgcn_mfma_f32_16x16x32_f16(a, bfrag[2], z, 0, 0, 0);
            f32x4 d3 = __builtin_amdgcn_mfma_f32_16x16x32_f16(a, bfrag[3], z, 0, 0, 0);
#pragma unroll
            for (int r = 0; r < 4; ++r) {        // C row = 4q+r = point
                int pv = __shfl((int)v, (g << 4) + (q << 2) + r, 64);
                int abase = (int)(((unsigned)pv) >> 24) * 65 + n;   // ml row
                float h0 = fmaxf(fmaf(d0[r], inv[0], bia[0]), 0.f);
                float h1 = fmaxf(fmaf(d1[r], inv[1], bia[1]), 0.f);
                float h2 = fmaxf(fmaf(d2[r], inv[2], bia[2]), 0.f);
                float h3 = fmaxf(fmaf(d3[r], inv[3], bia[3]), 0.f);
                atomicMax(&acc[abase +  0], __float_as_uint(h0));
                atomicMax(&acc[abase + 16], __float_as_uint(h1));
                atomicMax(&acc[abase + 32], __float_as_uint(h2));
                atomicMax(&acc[abase + 48], __float_as_uint(h3));
            }
        }
    }
    __syncthreads();

    // coalesced writeback of 128 pillars x 64 channels
    const int mbase = blockIdx.x * BPILL;
#pragma unroll
    for (int i = 0; i < (BPILL * C_OUT) / PBLK; ++i) {
        int wdx = i * PBLK + t;
        int row = wdx >> 6, c = wdx & 63;
        int m = mbase + row;
        if (m < M) out[(size_t)m * C_OUT + c] = __uint_as_float(acc[row * 65 + c]);
    }
}

extern "C" void kernel_launch(void* const* d_in, const int* in_sizes, int n_in,
                              void* d_out, int out_size, void* d_ws, size_t ws_size,
                              hipStream_t stream) {
    const float* gf    = (const float*)d_in[0];
    const int*   idx   = (const int*)  d_in[1];
    const float* W     = (const float*)d_in[3];
    const float* gamma = (const float*)d_in[4];
    const float* beta  = (const float*)d_in[5];
    const float* rmean = (const float*)d_in[6];
    const float* rvar  = (const float*)d_in[7];
    float*       out   = (float*)d_out;

    const int P  = in_sizes[0] / C_IN;
    const int M  = out_size / C_OUT;
    const int NB    = (M + BPILL - 1) >> BSHIFT;    // 1563 for M=200k
    const int NBpad = (NB + 32) & ~31;              // 1568 (> NB)
    const int E     = NREG * NBpad;                 // 12544 (region,bucket) entries
    const int NSB   = (P + SCHUNK - 1) / SCHUNK;    // 977

    char* ws = (char*)d_ws;
    auto align256 = [](size_t x) { return (x + 255) & ~(size_t)255; };
    int* tots   = (int*)ws;  ws += align256((size_t)E * 4);
    int* starts = (int*)ws;  ws += align256((size_t)(E + 1) * 4);
    int* cursor = (int*)ws;  ws += align256((size_t)E * 4);
    unsigned int* sorted = (unsigned int*)ws;       // P + 16*E u32 (~8.8 MB)

    hipMemsetAsync(tots, 0, (size_t)E * 4, stream);
    k_hist   <<<NSB, SBLK, 0, stream>>>(idx, tots, P, NBpad);
    k_scan   <<<1,   256, 0, stream>>>(tots, starts, cursor, E);
    k_padfill<<<(E + 255) / 256, 256, 0, stream>>>(tots, starts, sorted, E);
    k_split  <<<NSB, SBLK, 0, stream>>>(idx, cursor, sorted, P, NBpad);
    k_pool   <<<NB,  PBLK, 0, stream>>>(gf, sorted, starts, W, gamma, beta,
                                        rmean, rvar, out, M, NBpad);
}